// Round 9
// baseline (433.095 us; speedup 1.0000x reference)
//
#include <hip/hip_runtime.h>
#include <stdint.h>

// Binary BasicBlock: x ->(sign) conv1 ->BN1 ->(sign) conv2 ->BN2 -> +x
// B=64, C=256, H=W=28.  M = 64*784 = 50176 output pixels, N = 256, K = 9*256.
// Convs as exact i8 MFMA implicit-GEMM (binarized {-1,0,1}, int accum <= 2304
// -> bit-exact vs f32). Conv biases cancel in training-mode BN -> dropped.
//
// R9: R6 geometry (128x128 tile, K-unit=128, 128B rows, proven-0-conflict
// XOR swizzle, 2 barriers/unit, counted vmcnt) at 48KB LDS -> 3 blocks/CU.
// B is single-buffered in LDS, prefetched to REGISTERS one unit early (T14:
// issue global loads before COMPUTE for latency cover, ds_write after the
// barrier). A stays double-buffered via global_load_lds. R8 lesson: B frags
// must come from LDS, not per-unit L2 gathers (L2 thrashes under xb stream).

#define HW    784
#define MTOT  50176
#define BM    128
#define BN    128
#define MT    392          // MTOT/BM
#define NBLK  784          // MT * (256/BN)

typedef int   i32x4  __attribute__((ext_vector_type(4)));
typedef short shortx8 __attribute__((ext_vector_type(8)));
typedef float floatx4 __attribute__((ext_vector_type(4)));

typedef __attribute__((address_space(1))) const void gvoid_t;
typedef __attribute__((address_space(3))) void       lvoid_t;

__device__ __forceinline__ void gload16(const void* g, void* l) {
  __builtin_amdgcn_global_load_lds((gvoid_t*)g, (lvoid_t*)l, 16, 0, 0);
}

#define BAR()   __builtin_amdgcn_s_barrier()
#define VMW8()  asm volatile("s_waitcnt vmcnt(8)" ::: "memory")
#define VMW4()  asm volatile("s_waitcnt vmcnt(4)" ::: "memory")
#define VMW0()  asm volatile("s_waitcnt vmcnt(0)" ::: "memory")
#define LGKM0() asm volatile("s_waitcnt lgkmcnt(0)" ::: "memory")

// ---------------------------------------------------------------- prep+bin_x
__global__ __launch_bounds__(256) void prep(const float* __restrict__ w1,
                                            const float* __restrict__ w2,
                                            int8_t* __restrict__ wb1,
                                            int8_t* __restrict__ wb2,
                                            floatx4* __restrict__ zp,
                                            const float* __restrict__ x,
                                            int8_t* __restrict__ xb) {
  int bid = blockIdx.x;
  if (bid < 4609) {
    if (bid == 0) { zp[threadIdx.x] = (floatx4){0.f, 0.f, 0.f, 0.f}; return; }
    int base = bid - 1;
    const float* w = w1;
    int8_t* wbp = wb1;
    if (base >= 2304) { base -= 2304; w = w2; wbp = wb2; }
    int idx = base * 256 + threadIdx.x;      // < 589824
    int n = idx / 2304;
    int k = idx - n * 2304;
    int tap = k >> 8;
    int c = k & 255;
    float v = w[((size_t)n * 256 + c) * 9 + tap];
    wbp[idx] = (int8_t)((v > 0.f) - (v < 0.f));
    return;
  }
  int idx = bid - 4609;                      // < 3136
  const int mt = idx % 784, ct = idx / 784;
  __shared__ int8_t sh[64][68];
  const int t = threadIdx.x;
  const int tl = t & 63, th = t >> 6;
#pragma unroll
  for (int i = 0; i < 16; ++i) {
    int cl = th + i * 4;
    int c = ct * 64 + cl;
    int m = mt * 64 + tl;
    int b = m / HW, p = m - b * HW;
    float v = x[((size_t)b * 256 + c) * HW + p];   // coalesced along p
    sh[tl][cl] = (int8_t)((v > 0.f) - (v < 0.f));
  }
  __syncthreads();
#pragma unroll
  for (int i = 0; i < 16; ++i) {
    int ml = th + i * 4;
    xb[(size_t)(mt * 64 + ml) * 256 + ct * 64 + tl] = sh[ml][tl];
  }
}

// ---------------------------------------------------------------- conv (MFMA)
__global__ __launch_bounds__(256, 3) void bconv_mfma(
    const int8_t* __restrict__ xb, const int8_t* __restrict__ wb,
    int16_t* __restrict__ y, int* __restrict__ ssum, int* __restrict__ ssq,
    const int8_t* __restrict__ zp) {
  __shared__ int8_t lds_a[2][16384];            // A dbuf (128 rows x 128B)
  __shared__ int8_t lds_b[16384];               // B single (128 rows x 128B)
  const int tid = threadIdx.x;
  const int lane = tid & 63;
  const int wv = tid >> 6;                      // 4 waves
  const int wm = wv >> 1, wn = wv & 1;          // 2x2 wave grid, 64x64 each
  const int l15 = lane & 15;
  const int l4 = lane >> 4;

  int bid = blockIdx.x;
  int nb = (bid & 7) * (NBLK / 8) + (bid >> 3);
  const int mtile = nb >> 1, ntile = nb & 1;
  const int m0 = mtile * BM, n0 = ntile * BN;

  const int soff = ((lane & 7) ^ (lane >> 3)) << 4;
  int pyv[4], pxv[4], ldso[4];
  size_t pixb[4];
  const int8_t* wsrc[4];
#pragma unroll
  for (int j = 0; j < 4; ++j) {
    int r = wv * 32 + j * 8 + (lane >> 3);
    int m = m0 + r;
    int b = m / HW;
    int p = m - b * HW;
    pyv[j] = p / 28;
    pxv[j] = p - pyv[j] * 28;
    pixb[j] = (size_t)b * HW;
    wsrc[j] = wb + (size_t)(n0 + r) * 2304 + soff;
    ldso[j] = (wv * 32 + j * 8) * 128;
  }

  i32x4 acc[4][4];
#pragma unroll
  for (int a = 0; a < 4; ++a)
#pragma unroll
    for (int b = 0; b < 4; ++b) acc[a][b] = (i32x4){0, 0, 0, 0};

  auto STAGE_A = [&](int8_t* base, int unit) {   // 4 gload16/thread
    const int tap = unit >> 1;
    const int coff = (unit & 1) << 7;
    const int dy = tap / 3 - 1, dx = tap % 3 - 1;
#pragma unroll
    for (int j = 0; j < 4; ++j) {
      int yy = pyv[j] + dy, xx = pxv[j] + dx;
      const int8_t* sa = ((unsigned)yy < 28u && (unsigned)xx < 28u)
              ? xb + ((pixb[j] + yy * 28 + xx) << 8) + coff + soff
              : zp + soff;
      gload16(sa, base + ldso[j]);
    }
  };

  i32x4 bgP[4], bgQ[4];                          // B reg prefetch, ping-pong

#define BISSUE(DST, U)                                                         \
  _Pragma("unroll")                                                            \
  for (int j = 0; j < 4; ++j) DST[j] = *(const i32x4*)(wsrc[j] + (U) * 128);

#define BWRITE(SRC)                                                            \
  _Pragma("unroll")                                                            \
  for (int j = 0; j < 4; ++j)                                                  \
    *(i32x4*)(lds_b + ldso[j] + lane * 16) = SRC[j];

  auto COMPUTE = [&](const int8_t* abase) {
#pragma unroll
    for (int cc = 0; cc < 2; ++cc) {
      i32x4 af[4], bf[4];
      const int bc = cc * 4 + l4;
#pragma unroll
      for (int rb = 0; rb < 4; ++rb) {
        int row = wm * 64 + rb * 16 + l15;
        af[rb] = *(const i32x4*)(abase + row * 128 + ((bc ^ (row & 7)) << 4));
      }
#pragma unroll
      for (int nf = 0; nf < 4; ++nf) {
        int row = wn * 64 + nf * 16 + l15;
        bf[nf] = *(const i32x4*)(lds_b + row * 128 + ((bc ^ (row & 7)) << 4));
      }
      __builtin_amdgcn_s_setprio(1);
#pragma unroll
      for (int nf = 0; nf < 4; ++nf)
#pragma unroll
        for (int rb = 0; rb < 4; ++rb)
          acc[nf][rb] = __builtin_amdgcn_mfma_i32_16x16x64_i8(af[rb], bf[nf],
                                                              acc[nf][rb], 0, 0, 0);
      __builtin_amdgcn_s_setprio(0);
    }
  };

  BISSUE(bgP, 0)
  STAGE_A(lds_a[0], 0);
  BISSUE(bgQ, 1)
  STAGE_A(lds_a[1], 1);
  VMW8();
  BWRITE(bgP)
  LGKM0();
  BAR();

  for (int u = 0; u < 18; u += 2) {
    if (u + 2 < 18) { BISSUE(bgP, u + 2) }
    COMPUTE(lds_a[0]);
    BAR();
    if (u == 16) { VMW0(); } else { VMW4(); }
    BWRITE(bgQ)
    if (u + 2 < 18) STAGE_A(lds_a[0], u + 2);
    LGKM0();
    BAR();
    if (u + 3 < 18) { BISSUE(bgQ, u + 3) }
    COMPUTE(lds_a[1]);
    if (u + 1 < 17) {
      BAR();
      if (u + 1 == 15) { VMW0(); } else { VMW4(); }
      BWRITE(bgP)
      if (u + 3 < 18) STAGE_A(lds_a[1], u + 3);
      LGKM0();
      BAR();
    }
  }

  int sum_l[4] = {0, 0, 0, 0}, sq_l[4] = {0, 0, 0, 0};
#pragma unroll
  for (int nf = 0; nf < 4; ++nf) {
    const int n = n0 + wn * 64 + nf * 16 + l15;
#pragma unroll
    for (int rb = 0; rb < 4; ++rb) {
      const int mb = m0 + wm * 64 + rb * 16 + l4 * 4;
#pragma unroll
      for (int j = 0; j < 4; ++j) {
        int v = acc[nf][rb][j];
        y[(size_t)(mb + j) * 256 + n] = (int16_t)v;
        sum_l[nf] += v;
        sq_l[nf] += v * v;
      }
    }
  }
#pragma unroll
  for (int nf = 0; nf < 4; ++nf) {
    int s = sum_l[nf], q = sq_l[nf];
    s += __shfl_xor(s, 16); q += __shfl_xor(q, 16);
    s += __shfl_xor(s, 32); q += __shfl_xor(q, 32);
    if (lane < 16) {
      size_t off = (size_t)(mtile * 2 + wm) * 256 + (n0 + wn * 64 + nf * 16 + lane);
      ssum[off] = s;
      ssq[off] = q;
    }
  }
#undef BISSUE
#undef BWRITE
}

// ---------------------------------------------------------------- BN params
__global__ __launch_bounds__(256) void bn_params(const int* __restrict__ ssum,
                                                 const int* __restrict__ ssq,
                                                 const float* __restrict__ gamma,
                                                 float* __restrict__ params) {
  const int c = blockIdx.x;
  const int t = threadIdx.x;
  long long s = 0, q = 0;
  for (int e = t; e < MT * 2; e += 256) {
    s += ssum[(size_t)e * 256 + c];
    q += ssq[(size_t)e * 256 + c];
  }
  __shared__ long long sh[8];
  for (int off = 32; off; off >>= 1) { s += __shfl_down(s, off); q += __shfl_down(q, off); }
  int wv = t >> 6;
  if ((t & 63) == 0) { sh[wv] = s; sh[wv + 4] = q; }
  __syncthreads();
  if (t == 0) {
    s = sh[0] + sh[1] + sh[2] + sh[3];
    q = sh[4] + sh[5] + sh[6] + sh[7];
    double mean = (double)s / (double)MTOT;
    double var = (double)q / (double)MTOT - mean * mean;
    params[c * 2 + 0] = (float)mean;
    params[c * 2 + 1] = (float)((double)gamma[c] / sqrt(var + 1e-5));
  }
}

// ---------------------------------------------------------------- binarize mid
__global__ __launch_bounds__(256) void bin_mid(const int16_t* __restrict__ y,
                                               const float* __restrict__ params,
                                               const float* __restrict__ beta,
                                               int8_t* __restrict__ xb) {
  size_t i = ((size_t)blockIdx.x * 256 + threadIdx.x) * 8;
  shortx8 v = *(const shortx8*)(y + i);
  int cb = (int)(i & 255);
  union { int8_t b[8]; unsigned long long u; } o;
#pragma unroll
  for (int j = 0; j < 8; ++j) {
    int c = cb + j;
    float z = ((float)v[j] - params[c * 2]) * params[c * 2 + 1] + beta[c];
    o.b[j] = (int8_t)((z > 0.f) - (z < 0.f));
  }
  *(unsigned long long*)(xb + i) = o.u;
}

// ---------------------------------------------------------------- BN2 + resid
__global__ __launch_bounds__(256) void bn_residual(const int16_t* __restrict__ y,
                                                   const float* __restrict__ params,
                                                   const float* __restrict__ beta,
                                                   const float* __restrict__ x,
                                                   float* __restrict__ out) {
  const int mt = blockIdx.x, ct = blockIdx.y;
  __shared__ int16_t sh[64][66];
  const int t = threadIdx.x;
  const int tl = t & 63, th = t >> 6;
#pragma unroll
  for (int i = 0; i < 16; ++i) {
    int ml = th + i * 4;
    sh[ml][tl] = y[(size_t)(mt * 64 + ml) * 256 + ct * 64 + tl];
  }
  __syncthreads();
#pragma unroll
  for (int i = 0; i < 16; ++i) {
    int cl = th + i * 4;
    int c = ct * 64 + cl;
    int m = mt * 64 + tl;
    int b = m / HW, p = m - b * HW;
    size_t oi = ((size_t)b * 256 + c) * HW + p;
    float z = ((float)sh[tl][cl] - params[c * 2]) * params[c * 2 + 1] + beta[c];
    out[oi] = z + x[oi];
  }
}

// ---------------------------------------------------------------- launch
extern "C" void kernel_launch(void* const* d_in, const int* in_sizes, int n_in,
                              void* d_out, int out_size, void* d_ws, size_t ws_size,
                              hipStream_t stream) {
  const float* x      = (const float*)d_in[0];
  const float* w1     = (const float*)d_in[1];
  const float* gamma1 = (const float*)d_in[3];
  const float* beta1  = (const float*)d_in[4];
  const float* w2     = (const float*)d_in[5];
  const float* gamma2 = (const float*)d_in[7];
  const float* beta2  = (const float*)d_in[8];
  float* out = (float*)d_out;

  char* ws = (char*)d_ws;
  int8_t*  zp      = (int8_t*)ws;
  int8_t*  wb1     = (int8_t*)(ws + 4096);
  int8_t*  wb2     = (int8_t*)(ws + 593920);
  float*   params1 = (float*)(ws + 1183744);
  float*   params2 = (float*)(ws + 1185792);
  int*     ssum    = (int*)(ws + 1187840);
  int*     ssq     = (int*)(ws + 1990656);
  int8_t*  xb      = (int8_t*)(ws + 2793472);
  int16_t* yb      = (int16_t*)(ws + 15638528);
  if (ws_size < 41328640ull) return;

  dim3 tr(784, 4);
  prep<<<7745, 256, 0, stream>>>(w1, w2, wb1, wb2, (floatx4*)zp, x, xb);
  bconv_mfma<<<NBLK, 256, 0, stream>>>(xb, wb1, yb, ssum, ssq, zp);
  bn_params<<<256, 256, 0, stream>>>(ssum, ssq, gamma1, params1);
  bin_mid<<<6272, 256, 0, stream>>>(yb, params1, beta1, xb);
  bconv_mfma<<<NBLK, 256, 0, stream>>>(xb, wb2, yb, ssum, ssq, zp);
  bn_params<<<256, 256, 0, stream>>>(ssum, ssq, gamma2, params2);
  bn_residual<<<tr, 256, 0, stream>>>(yb, params2, beta2, x, out);
}

// Round 10
// 198.830 us; speedup vs baseline: 2.1782x; 2.1782x over previous
//
#include <hip/hip_runtime.h>
#include <stdint.h>

// Binary BasicBlock: x ->(sign) conv1 ->BN1 ->(sign) conv2 ->BN2 -> +x
// B=64, C=256, H=W=28.  M = 64*784 = 50176 output pixels, N = 256, K = 9*256.
// Convs as exact i8 MFMA implicit-GEMM (binarized {-1,0,1}, int accum <= 2304
// -> bit-exact vs f32). Conv biases cancel in training-mode BN -> dropped.
//
// R10: 256x256 block tile, 512 threads (8 waves, 2x4 grid), wave tile 128x64
// -> LDS bytes/op 1/64 -> 1/85 and 64 MFMA per barrier phase (2x R6).
// K-unit=128 kept: 128B rows + slot^(row&7) swizzle (only layout measured
// conflict-free: R4/R6 0 conflicts vs R2/R5/R7 3.6M/2.7M/3.6M).
// A+B double-buffered = 128KB LDS, 1 block/CU, grid 196 (=M/256), bijective
// XCD swizzle (m204; 196%8!=0). R6-verified counted-vmcnt ledger: 8 gloads
// per unit per thread, VM8 steady / VM0 tail, 2 barriers per unit.
// R9 lesson: no reg-staged B (spilled to scratch: 161MB writes).

#define HW    784
#define MTOT  50176
#define BM    256
#define BN    256
#define MT    196          // MTOT/BM
#define NBLK  196          // MT (BN covers all of N)

typedef int   i32x4  __attribute__((ext_vector_type(4)));
typedef short shortx8 __attribute__((ext_vector_type(8)));
typedef float floatx4 __attribute__((ext_vector_type(4)));

typedef __attribute__((address_space(1))) const void gvoid_t;
typedef __attribute__((address_space(3))) void       lvoid_t;

__device__ __forceinline__ void gload16(const void* g, void* l) {
  // async global->LDS, 16B/lane; LDS dest = wave-uniform base + lane*16
  __builtin_amdgcn_global_load_lds((gvoid_t*)g, (lvoid_t*)l, 16, 0, 0);
}

#define BAR()  __builtin_amdgcn_s_barrier()
#define VM8()  asm volatile("s_waitcnt vmcnt(8)" ::: "memory")
#define VM0()  asm volatile("s_waitcnt vmcnt(0)" ::: "memory")

// ---------------------------------------------------------------- prep+bin_x
// blocks 0..4608: {zero page | wb1 | wb2}; blocks 4609..7744: bin_x transpose
// w OIHW [256][256][3][3] -> wb [n][k], k = tap*256 + c  (tap = ky*3+kx)
// x NCHW f32 -> xb NHWC i8 via LDS transpose tile (64 m x 64 c)
__global__ __launch_bounds__(256) void prep(const float* __restrict__ w1,
                                            const float* __restrict__ w2,
                                            int8_t* __restrict__ wb1,
                                            int8_t* __restrict__ wb2,
                                            floatx4* __restrict__ zp,
                                            const float* __restrict__ x,
                                            int8_t* __restrict__ xb) {
  int bid = blockIdx.x;
  if (bid < 4609) {
    if (bid == 0) { zp[threadIdx.x] = (floatx4){0.f, 0.f, 0.f, 0.f}; return; }
    int base = bid - 1;
    const float* w = w1;
    int8_t* wbp = wb1;
    if (base >= 2304) { base -= 2304; w = w2; wbp = wb2; }
    int idx = base * 256 + threadIdx.x;      // < 589824
    int n = idx / 2304;
    int k = idx - n * 2304;
    int tap = k >> 8;
    int c = k & 255;
    float v = w[((size_t)n * 256 + c) * 9 + tap];
    wbp[idx] = (int8_t)((v > 0.f) - (v < 0.f));
    return;
  }
  int idx = bid - 4609;                      // < 3136
  const int mt = idx % 784, ct = idx / 784;
  __shared__ int8_t sh[64][68];
  const int t = threadIdx.x;
  const int tl = t & 63, th = t >> 6;
#pragma unroll
  for (int i = 0; i < 16; ++i) {
    int cl = th + i * 4;
    int c = ct * 64 + cl;
    int m = mt * 64 + tl;
    int b = m / HW, p = m - b * HW;
    float v = x[((size_t)b * 256 + c) * HW + p];   // coalesced along p
    sh[tl][cl] = (int8_t)((v > 0.f) - (v < 0.f));
  }
  __syncthreads();
#pragma unroll
  for (int i = 0; i < 16; ++i) {
    int ml = th + i * 4;
    xb[(size_t)(mt * 64 + ml) * 256 + ct * 64 + tl] = sh[ml][tl];
  }
}

// ---------------------------------------------------------------- conv (MFMA)
// xb [M][256] i8 NHWC, wb [256][2304] i8 -> y [M][256] i16 NHWC
// + per-(mtile,wave_m) channel partial sum / sumsq (exact i32, no atomics)
__global__ __launch_bounds__(512, 2) void bconv_mfma(
    const int8_t* __restrict__ xb, const int8_t* __restrict__ wb,
    int16_t* __restrict__ y, int* __restrict__ ssum, int* __restrict__ ssq,
    const int8_t* __restrict__ zp) {
  // A dbuf [2][256x128B] at 0, B dbuf [2][256x128B] at 65536 -> 128KB total
  __shared__ int8_t lds[131072];
  const int tid = threadIdx.x;
  const int lane = tid & 63;
  const int wv = tid >> 6;                      // 8 waves
  const int wm = wv >> 2, wn = wv & 3;          // 2x4 grid, wave tile 128x64
  const int l15 = lane & 15;
  const int l4 = lane >> 4;

  // bijective XCD swizzle (m204): nwg=196, q=24, r=4
  int bid = blockIdx.x;
  const int xcd = bid & 7, kk = bid >> 3;       // kk in 0..24
  const int mtile = (xcd < 4) ? (xcd * 25 + kk) : (100 + (xcd - 4) * 24 + kk);
  const int m0 = mtile * BM;

  // staging: call j (0..3) covers rows [j*64, j*64+64); this thread's row
  // r = j*64 + wv*8 + (lane>>3); r&7 == lane>>3 -> source pre-swizzle offset
  // is call-independent. LDS 16B-slot (lane&7) of row r holds global chunk
  // ((lane&7)^(r&7)).
  const int soff = ((lane & 7) ^ (lane >> 3)) << 4;
  int pyv[4], pxv[4], ldso[4];
  size_t pixb[4];
  const int8_t* wsrc[4];
#pragma unroll
  for (int j = 0; j < 4; ++j) {
    int r = j * 64 + wv * 8 + (lane >> 3);
    int m = m0 + r;
    int b = m / HW;
    int p = m - b * HW;
    pyv[j] = p / 28;
    pxv[j] = p - pyv[j] * 28;
    pixb[j] = (size_t)b * HW;
    wsrc[j] = wb + (size_t)r * 2304 + soff;     // B row n = r (BN = full N)
    ldso[j] = (j * 64 + wv * 8) * 128;          // wave-uniform LDS base
  }

  i32x4 acc[4][8];
#pragma unroll
  for (int a = 0; a < 4; ++a)
#pragma unroll
    for (int b = 0; b < 8; ++b) acc[a][b] = (i32x4){0, 0, 0, 0};

  // unit u = tap*2 + h : tap = u>>1 (0..8), K-half h = u&1 (channel 128-block)
  // STAGE = 8 gload16/thread (A 4 + B 4) -> vmcnt granularity 8.
  auto STAGE = [&](int buf, int unit) {
    const int tap = unit >> 1;
    const int coff = (unit & 1) << 7;
    const int dy = tap / 3 - 1, dx = tap % 3 - 1;
    int8_t* abase = lds + buf * 32768;
    int8_t* bbase = lds + 65536 + buf * 32768;
#pragma unroll
    for (int j = 0; j < 4; ++j) {
      int yy = pyv[j] + dy, xx = pxv[j] + dx;
      const int8_t* sa = ((unsigned)yy < 28u && (unsigned)xx < 28u)
              ? xb + ((pixb[j] + yy * 28 + xx) << 8) + coff + soff
              : zp + soff;
      gload16(sa, abase + ldso[j]);                      // A 256x128B
      gload16(wsrc[j] + unit * 128, bbase + ldso[j]);    // B 256x128B
    }
  };

  auto COMPUTE = [&](int buf) {
    const int8_t* abase = lds + buf * 32768;
    const int8_t* bbase = lds + 65536 + buf * 32768;
#pragma unroll
    for (int cc = 0; cc < 2; ++cc) {            // K chunks of 64 within unit
      i32x4 af[8], bf[4];
      const int bc = cc * 4 + l4;               // 16B slot index 0..7
#pragma unroll
      for (int rb = 0; rb < 8; ++rb) {
        int row = wm * 128 + rb * 16 + l15;
        af[rb] = *(const i32x4*)(abase + row * 128 + ((bc ^ (row & 7)) << 4));
      }
#pragma unroll
      for (int nf = 0; nf < 4; ++nf) {
        int row = wn * 64 + nf * 16 + l15;
        bf[nf] = *(const i32x4*)(bbase + row * 128 + ((bc ^ (row & 7)) << 4));
      }
      __builtin_amdgcn_s_setprio(1);            // T5
#pragma unroll
      for (int nf = 0; nf < 4; ++nf)
#pragma unroll
        for (int rb = 0; rb < 8; ++rb)
          acc[nf][rb] = __builtin_amdgcn_mfma_i32_16x16x64_i8(af[rb], bf[nf],
                                                              acc[nf][rb], 0, 0, 0);
      __builtin_amdgcn_s_setprio(0);
    }
  };

  // R6-verified counted-vmcnt schedule, scaled: 64 MFMA per phase per wave.
  STAGE(0, 0);
  STAGE(1, 1);                                  // 16 outstanding
  VM8();                                        // unit 0 landed (in-order)
  BAR();
  for (int u = 0; u < 18; u += 2) {
    COMPUTE(0);                                 // unit u
    BAR();                                      // all waves done reading buf0
    if (u + 2 < 18) { STAGE(0, u + 2); VM8(); } // unit u+1 landed, u+2 in flight
    else            { VM0(); }                  // u=16: wait unit 17
    BAR();
    COMPUTE(1);                                 // unit u+1
    BAR();                                      // all waves done reading buf1
    if (u + 3 < 18) { STAGE(1, u + 3); VM8(); }
    BAR();
  }

  // epilogue: store y (i16 NHWC) + exact per-channel partials
  int sum_l[4] = {0, 0, 0, 0}, sq_l[4] = {0, 0, 0, 0};
#pragma unroll
  for (int nf = 0; nf < 4; ++nf) {
    const int n = wn * 64 + nf * 16 + l15;        // C/D: col = lane&15 (m89)
#pragma unroll
    for (int rb = 0; rb < 8; ++rb) {
      const int mb = m0 + wm * 128 + rb * 16 + l4 * 4;  // row = (lane>>4)*4 + j
#pragma unroll
      for (int j = 0; j < 4; ++j) {
        int v = acc[nf][rb][j];
        y[(size_t)(mb + j) * 256 + n] = (int16_t)v;
        sum_l[nf] += v;
        sq_l[nf] += v * v;                        // <= 32*2304^2 = 1.7e8, fits i32
      }
    }
  }
#pragma unroll
  for (int nf = 0; nf < 4; ++nf) {
    int s = sum_l[nf], q = sq_l[nf];
    s += __shfl_xor(s, 16); q += __shfl_xor(q, 16);
    s += __shfl_xor(s, 32); q += __shfl_xor(q, 32);
    if (lane < 16) {
      size_t off = (size_t)(mtile * 2 + wm) * 256 + (wn * 64 + nf * 16 + lane);
      ssum[off] = s;                              // unique writer per slot
      ssq[off] = q;
    }
  }
}

// ---------------------------------------------------------------- BN params
// reduce [MT*2][256] partials -> per-channel mean & gamma*rsqrt(var+eps)
__global__ __launch_bounds__(256) void bn_params(const int* __restrict__ ssum,
                                                 const int* __restrict__ ssq,
                                                 const float* __restrict__ gamma,
                                                 float* __restrict__ params) {
  const int c = blockIdx.x;
  const int t = threadIdx.x;
  long long s = 0, q = 0;
  for (int e = t; e < MT * 2; e += 256) {        // 392 slot rows (128 m each)
    s += ssum[(size_t)e * 256 + c];
    q += ssq[(size_t)e * 256 + c];
  }
  __shared__ long long sh[8];
  for (int off = 32; off; off >>= 1) { s += __shfl_down(s, off); q += __shfl_down(q, off); }
  int wv = t >> 6;
  if ((t & 63) == 0) { sh[wv] = s; sh[wv + 4] = q; }
  __syncthreads();
  if (t == 0) {
    s = sh[0] + sh[1] + sh[2] + sh[3];
    q = sh[4] + sh[5] + sh[6] + sh[7];
    double mean = (double)s / (double)MTOT;
    double var = (double)q / (double)MTOT - mean * mean;
    params[c * 2 + 0] = (float)mean;
    params[c * 2 + 1] = (float)((double)gamma[c] / sqrt(var + 1e-5));
  }
}

// ---------------------------------------------------------------- binarize mid
// xb = sign((y - mean)*inv + beta)   (bias cancels in BN)
__global__ __launch_bounds__(256) void bin_mid(const int16_t* __restrict__ y,
                                               const float* __restrict__ params,
                                               const float* __restrict__ beta,
                                               int8_t* __restrict__ xb) {
  size_t i = ((size_t)blockIdx.x * 256 + threadIdx.x) * 8;
  shortx8 v = *(const shortx8*)(y + i);
  int cb = (int)(i & 255);
  union { int8_t b[8]; unsigned long long u; } o;
#pragma unroll
  for (int j = 0; j < 8; ++j) {
    int c = cb + j;
    float z = ((float)v[j] - params[c * 2]) * params[c * 2 + 1] + beta[c];
    o.b[j] = (int8_t)((z > 0.f) - (z < 0.f));
  }
  *(unsigned long long*)(xb + i) = o.u;
}

// ---------------------------------------------------------------- BN2 + resid
// out NCHW f32 = (y2 - mean)*inv + beta + x ; y2 read NHWC via LDS transpose
__global__ __launch_bounds__(256) void bn_residual(const int16_t* __restrict__ y,
                                                   const float* __restrict__ params,
                                                   const float* __restrict__ beta,
                                                   const float* __restrict__ x,
                                                   float* __restrict__ out) {
  const int mt = blockIdx.x, ct = blockIdx.y;
  __shared__ int16_t sh[64][66];
  const int t = threadIdx.x;
  const int tl = t & 63, th = t >> 6;
#pragma unroll
  for (int i = 0; i < 16; ++i) {
    int ml = th + i * 4;
    sh[ml][tl] = y[(size_t)(mt * 64 + ml) * 256 + ct * 64 + tl];  // coalesced
  }
  __syncthreads();
#pragma unroll
  for (int i = 0; i < 16; ++i) {
    int cl = th + i * 4;
    int c = ct * 64 + cl;
    int m = mt * 64 + tl;
    int b = m / HW, p = m - b * HW;
    size_t oi = ((size_t)b * 256 + c) * HW + p;
    float z = ((float)sh[tl][cl] - params[c * 2]) * params[c * 2 + 1] + beta[c];
    out[oi] = z + x[oi];                         // coalesced along p
  }
}

// ---------------------------------------------------------------- launch
extern "C" void kernel_launch(void* const* d_in, const int* in_sizes, int n_in,
                              void* d_out, int out_size, void* d_ws, size_t ws_size,
                              hipStream_t stream) {
  const float* x      = (const float*)d_in[0];
  const float* w1     = (const float*)d_in[1];
  const float* gamma1 = (const float*)d_in[3];
  const float* beta1  = (const float*)d_in[4];
  const float* w2     = (const float*)d_in[5];
  const float* gamma2 = (const float*)d_in[7];
  const float* beta2  = (const float*)d_in[8];
  float* out = (float*)d_out;

  // ws layout (bytes):
  char* ws = (char*)d_ws;
  int8_t*  zp      = (int8_t*)ws;                       //        0 : 4096 zero page
  int8_t*  wb1     = (int8_t*)(ws + 4096);              //   589824
  int8_t*  wb2     = (int8_t*)(ws + 593920);            //   589824
  float*   params1 = (float*)(ws + 1183744);            //     2048
  float*   params2 = (float*)(ws + 1185792);            //     2048
  int*     ssum    = (int*)(ws + 1187840);              //   802816 (392*256*4 used)
  int*     ssq     = (int*)(ws + 1990656);              //   802816
  int8_t*  xb      = (int8_t*)(ws + 2793472);           // 12845056 (reused conv1/conv2 input)
  int16_t* yb      = (int16_t*)(ws + 15638528);         // 25690112 (reused y1/y2)
  if (ws_size < 41328640ull) return;                    // need ~39.4 MiB scratch

  dim3 tr(784, 4);
  prep<<<7745, 256, 0, stream>>>(w1, w2, wb1, wb2, (floatx4*)zp, x, xb);
  bconv_mfma<<<NBLK, 512, 0, stream>>>(xb, wb1, yb, ssum, ssq, zp);
  bn_params<<<256, 256, 0, stream>>>(ssum, ssq, gamma1, params1);
  bin_mid<<<6272, 256, 0, stream>>>(yb, params1, beta1, xb);
  bconv_mfma<<<NBLK, 512, 0, stream>>>(xb, wb2, yb, ssum, ssq, zp);
  bn_params<<<256, 256, 0, stream>>>(ssum, ssq, gamma2, params2);
  bn_residual<<<tr, 256, 0, stream>>>(yb, params2, beta2, x, out);
}

// Round 11
// 142.901 us; speedup vs baseline: 3.0307x; 1.3914x over previous
//
#include <hip/hip_runtime.h>
#include <stdint.h>

// Binary BasicBlock: x ->(sign) conv1 ->BN1 ->(sign) conv2 ->BN2 -> +x
// B=64, C=256, H=W=28.  M = 50176 valid pixels, N = 256, K = 9*256.
// Convs as exact i8 MFMA implicit-GEMM (binarized {-1,0,1}, int accum <= 2304
// -> bit-exact vs f32). Conv biases cancel in training-mode BN -> dropped.
//
// R11: PADDED activation layout kills all conv geometry in the hot loop.
// xb_pad: per image 29x29 (shared zero border col x'=28 / row y'=28),
// mp = 31 + b*841 + y*29 + x; tap read = row shift o = dy*29+dx (always valid).
// A (192 halo rows x 256B, as 2 planes of 128B rows - proven swizzle) staged
// ONCE per block; only B dbuf-staged per unit (4 gloads) with R6's proven
// 2-barrier counted-vmcnt rhythm. Invalid pad rows masked at epilogue.
// Stats via 32-bucket i64 atomicAdd (exact, low contention). LDS 80KB ->
// 2 blocks/CU. R9/R10 lesson: acc stays 64 VGPRs (no-spill regime).

#define HW    784
#define MTOT  50176
#define BM    128
#define BN    128
#define MTILES 421         // ceil(53888/128): grid rows cover pad+images
#define NBLK  842          // MTILES * 2
#define ROWSP 53921        // 31 lead + 64*841 + trailing halo

typedef int   i32x4  __attribute__((ext_vector_type(4)));
typedef int   int4v  __attribute__((ext_vector_type(4)));
typedef short shortx8 __attribute__((ext_vector_type(8)));
typedef unsigned long long ull;

typedef __attribute__((address_space(1))) const void gvoid_t;
typedef __attribute__((address_space(3))) void       lvoid_t;

__device__ __forceinline__ void gload16(const void* g, void* l) {
  // async global->LDS, 16B/lane; LDS dest = wave-uniform base + lane*16
  __builtin_amdgcn_global_load_lds((gvoid_t*)g, (lvoid_t*)l, 16, 0, 0);
}

#define BAR()  __builtin_amdgcn_s_barrier()
#define VMW4() asm volatile("s_waitcnt vmcnt(4)" ::: "memory")
#define VMW0() asm volatile("s_waitcnt vmcnt(0)" ::: "memory")

// ---------------------------------------------------------------- prep
// bid 0: zero page + stats buckets; 1..4608: wb1/wb2 binarize;
// 4609..4672: per-image borders; 4673: lead/trail pad; 4674..7809: bin_x.
__global__ __launch_bounds__(256) void prep(const float* __restrict__ w1,
                                            const float* __restrict__ w2,
                                            int8_t* __restrict__ wb1,
                                            int8_t* __restrict__ wb2,
                                            int4v* __restrict__ zp,
                                            ull* __restrict__ stats,   // both, 262144B
                                            const float* __restrict__ x,
                                            int8_t* __restrict__ xbp) {
  const int bid = blockIdx.x;
  const int t = threadIdx.x;
  if (bid == 0) {
    if (t < 256) zp[t] = (int4v){0, 0, 0, 0};
#pragma unroll
    for (int k = 0; k < 64; ++k) ((int4v*)stats)[t + k * 256] = (int4v){0, 0, 0, 0};
    return;
  }
  if (bid < 4609) {
    int base = bid - 1;
    const float* w = w1;
    int8_t* wbp = wb1;
    if (base >= 2304) { base -= 2304; w = w2; wbp = wb2; }
    int idx = base * 256 + t;
    int n = idx / 2304;
    int k = idx - n * 2304;
    int tap = k >> 8;
    int c = k & 255;
    float v = w[((size_t)n * 256 + c) * 9 + tap];
    wbp[idx] = (int8_t)((v > 0.f) - (v < 0.f));
    return;
  }
  if (bid < 4673) {                            // image borders: 57 rows each
    int img = bid - 4609;
    size_t ibase = 31 + (size_t)img * 841;
    int r = t >> 2, part = t & 3;              // threads 0..227 used
    if (r < 57) {
      size_t mp = (r < 29) ? ibase + 812 + r             // y'=28 row
                           : ibase + (size_t)(r - 29) * 29 + 28;  // x'=28 col
      int4v* p = (int4v*)(xbp + mp * 256);
#pragma unroll
      for (int k = 0; k < 4; ++k) p[part * 4 + k] = (int4v){0, 0, 0, 0};
    }
    return;
  }
  if (bid == 4673) {                           // lead 0..30 + trail 53856..53920
#pragma unroll
    for (int k = 0; k < 6; ++k) {
      int idx = t + k * 256;                   // 96 rows * 16 int4 = 1536
      int row = idx >> 4, slot = idx & 15;
      size_t mp = (row < 31) ? (size_t)row : (size_t)(53856 + row - 31);
      ((int4v*)(xbp + mp * 256))[slot] = (int4v){0, 0, 0, 0};
    }
    return;
  }
  // bin_x: x NCHW f32 -> xb_pad i8 via LDS transpose tile (64 m x 64 c)
  int idx = bid - 4674;                        // < 3136
  const int mt = idx % 784, ct = idx / 784;
  __shared__ int8_t sh[64][68];
  const int tl = t & 63, th = t >> 6;
#pragma unroll
  for (int i = 0; i < 16; ++i) {
    int cl = th + i * 4;
    int c = ct * 64 + cl;
    int m = mt * 64 + tl;
    int b = m / HW, p = m - b * HW;
    float v = x[((size_t)b * 256 + c) * HW + p];   // coalesced along p
    sh[tl][cl] = (int8_t)((v > 0.f) - (v < 0.f));
  }
  __syncthreads();
#pragma unroll
  for (int i = 0; i < 16; ++i) {
    int ml = th + i * 4;
    int m = mt * 64 + ml;
    int b = m / HW, p = m - b * HW;
    int yy = p / 28, xx = p - yy * 28;
    size_t mp = 31 + (size_t)b * 841 + (size_t)yy * 29 + xx;
    xbp[mp * 256 + ct * 64 + tl] = sh[ml][tl];
  }
}

// ---------------------------------------------------------------- conv (MFMA)
// xbp [ROWSP][256] i8 padded, wb [256][2304] i8 -> y [M][256] i16 (valid rows)
// + per-channel stats via 32-bucket i64 atomics (exact).
__global__ __launch_bounds__(256, 2) void bconv_mfma(
    const int8_t* __restrict__ xb, const int8_t* __restrict__ wb,
    int16_t* __restrict__ y, ull* __restrict__ stats,
    const int8_t* __restrict__ zp) {
  // A: 2 planes x 192 rows x 128B = 48KB (staged once); B: dbuf 2 x 16KB.
  __shared__ int8_t lds[81920];
  int8_t* lds_a = lds;                         // planes at 0 / 24576
  int8_t* lds_b = lds + 49152;                 // bufs at 0 / 16384
  const int tid = threadIdx.x;
  const int lane = tid & 63;
  const int wv = tid >> 6;                      // 4 waves
  const int wm = wv >> 1, wn = wv & 1;          // 2x2 wave grid, 64x64 each
  const int l15 = lane & 15;
  const int l4 = lane >> 4;

  // bijective XCD swizzle (m204): nwg=842, q=105, r=2
  const int bid = blockIdx.x;
  const int xcd = bid & 7, ii = bid >> 3;
  const int nb = (xcd < 2 ? xcd * 106 : 212 + (xcd - 2) * 105) + ii;
  const int mtile = nb >> 1, ntile = nb & 1;
  const int mp0 = mtile * BM, n0 = ntile * BN;

  // shared swizzle: LDS slot (lane&7) of row r holds source chunk
  // ((lane&7)^(r&7)); staging rows are 8-aligned per call so r&7 == lane>>3.
  const int cs8 = (lane & 7) ^ (lane >> 3);

  // ---- A: stage 192 halo rows x 256B ONCE, split into 2 planes of 128B rows
  {
    const int rsub = lane >> 3;
#pragma unroll
    for (int j = 0; j < 12; ++j) {
      const int h = j & 1;
      const int Lr = wv * 48 + (j >> 1) * 8 + rsub;
      const int gr = mp0 - 31 + Lr;            // may be <0 only for mtile 0
      const int8_t* src = (gr >= 0)
              ? xb + (size_t)gr * 256 + h * 128 + cs8 * 16
              : zp + cs8 * 16;
      gload16(src, lds_a + h * 24576 + (wv * 48 + (j >> 1) * 8) * 128 + lane * 16);
    }
  }

  // ---- B staging precompute (R6 verbatim): 4 gload16/unit/thread
  const int8_t* wsrc[4];
  int ldsoB[4];
#pragma unroll
  for (int j = 0; j < 4; ++j) {
    int r = wv * 32 + j * 8 + (lane >> 3);
    wsrc[j] = wb + (size_t)(n0 + r) * 2304 + cs8 * 16;
    ldsoB[j] = (wv * 32 + j * 8) * 128;
  }

  i32x4 acc[4][4];
#pragma unroll
  for (int a = 0; a < 4; ++a)
#pragma unroll
    for (int b = 0; b < 4; ++b) acc[a][b] = (i32x4){0, 0, 0, 0};

  auto STAGE_B = [&](int sel, int unit) {
    int8_t* base = lds_b + sel * 16384;
#pragma unroll
    for (int j = 0; j < 4; ++j)
      gload16(wsrc[j] + unit * 128, base + ldsoB[j]);
  };

  // tap row-shift offsets dy*29+dx (padded layout: always valid)
  constexpr int OFF[9] = {-30, -29, -28, -1, 0, 1, 28, 29, 30};

  auto COMPUTE = [&](int u, int sel) {
    const int o31 = OFF[u >> 1] + 31;          // compile-time under unroll
    const int8_t* aplane = lds_a + (u & 1) * 24576;
    const int8_t* bbase = lds_b + sel * 16384;
#pragma unroll
    for (int cc = 0; cc < 2; ++cc) {
      i32x4 af[4], bf[4];
      const int bc = cc * 4 + l4;              // 16B slot 0..7
#pragma unroll
      for (int rb = 0; rb < 4; ++rb) {
        int rl = wm * 64 + rb * 16 + l15 + o31;  // local halo row 1..188
        af[rb] = *(const i32x4*)(aplane + rl * 128 + ((bc ^ (rl & 7)) << 4));
      }
#pragma unroll
      for (int nf = 0; nf < 4; ++nf) {
        int row = wn * 64 + nf * 16 + l15;
        bf[nf] = *(const i32x4*)(bbase + row * 128 + ((bc ^ (row & 7)) << 4));
      }
      __builtin_amdgcn_s_setprio(1);           // T5
#pragma unroll
      for (int nf = 0; nf < 4; ++nf)
#pragma unroll
        for (int rb = 0; rb < 4; ++rb)
          acc[nf][rb] = __builtin_amdgcn_mfma_i32_16x16x64_i8(af[rb], bf[nf],
                                                              acc[nf][rb], 0, 0, 0);
      __builtin_amdgcn_s_setprio(0);
    }
  };

  // prologue: A(12) + B0(4) + B1(4) issued; vmcnt(4) -> A,B0 landed.
  STAGE_B(0, 0);
  STAGE_B(1, 1);
  VMW4();
  BAR();
#pragma unroll
  for (int u = 0; u < 18; ++u) {
    COMPUTE(u, u & 1);
    BAR();                                     // all waves done with buf u&1
    if (u + 2 < 18) { STAGE_B(u & 1, u + 2); VMW4(); }  // B(u+1) certified
    else if (u == 16) { VMW0(); }              // tail: B17 landed
    BAR();
  }

  // epilogue: masked y write (valid rows only) + exact stats via atomics
  int sum_l[4] = {0, 0, 0, 0}, sq_l[4] = {0, 0, 0, 0};
#pragma unroll
  for (int rb = 0; rb < 4; ++rb) {
#pragma unroll
    for (int jj = 0; jj < 4; ++jj) {
      const int mp = mp0 + wm * 64 + rb * 16 + l4 * 4 + jj;
      const int tt = mp - 31;
      int valid = (tt >= 0);
      unsigned b = (unsigned)tt / 841u;
      unsigned q = (unsigned)tt - b * 841u;
      unsigned yy = q / 29u;
      unsigned xx = q - yy * 29u;
      valid &= (b < 64u) & (yy < 28u) & (xx < 28u);
      const size_t m = (size_t)b * HW + yy * 28 + xx;
#pragma unroll
      for (int nf = 0; nf < 4; ++nf) {
        int v = acc[nf][rb][jj];
        if (valid) {
          y[m * 256 + (n0 + wn * 64 + nf * 16 + l15)] = (int16_t)v;
          sum_l[nf] += v;
          sq_l[nf] += v * v;                   // <= 16*2304^2 per lane, i32 ok
        }
      }
    }
  }
  const int bucket = bid & 31;
#pragma unroll
  for (int nf = 0; nf < 4; ++nf) {
    int s = sum_l[nf], q = sq_l[nf];
    s += __shfl_xor(s, 16); q += __shfl_xor(q, 16);
    s += __shfl_xor(s, 32); q += __shfl_xor(q, 32);
    if (lane < 16) {
      int n = n0 + wn * 64 + nf * 16 + lane;
      ull* slot = stats + ((size_t)(bucket * 256 + n) << 1);
      atomicAdd(slot, (ull)(long long)s);      // exact: integer wrap-safe
      atomicAdd(slot + 1, (ull)(long long)q);
    }
  }
}

// ---------------------------------------------------------------- BN params
// sum 32 buckets -> mean & gamma/sqrt(var+eps); re-zero buckets for replay.
__global__ __launch_bounds__(256) void bn_params(ull* __restrict__ stats,
                                                 const float* __restrict__ gamma,
                                                 float* __restrict__ params) {
  const int c = threadIdx.x;
  long long s = 0, q = 0;
#pragma unroll
  for (int k = 0; k < 32; ++k) {
    s += (long long)stats[(size_t)(k * 256 + c) * 2 + 0];
    q += (long long)stats[(size_t)(k * 256 + c) * 2 + 1];
  }
  double mean = (double)s / (double)MTOT;
  double var = (double)q / (double)MTOT - mean * mean;
  params[c * 2 + 0] = (float)mean;
  params[c * 2 + 1] = (float)((double)gamma[c] / sqrt(var + 1e-5));
#pragma unroll
  for (int k = 0; k < 32; ++k) {
    stats[(size_t)(k * 256 + c) * 2 + 0] = 0;
    stats[(size_t)(k * 256 + c) * 2 + 1] = 0;
  }
}

// ---------------------------------------------------------------- binarize mid
// xb_pad interior = sign((y - mean)*inv + beta); borders stay zero from prep.
__global__ __launch_bounds__(256) void bin_mid(const int16_t* __restrict__ y,
                                               const float* __restrict__ params,
                                               const float* __restrict__ beta,
                                               int8_t* __restrict__ xbp) {
  size_t i = ((size_t)blockIdx.x * 256 + threadIdx.x) * 8;
  shortx8 v = *(const shortx8*)(y + i);
  int cb = (int)(i & 255);
  int m = (int)(i >> 8);
  int b = m / HW, p = m - b * HW;
  int yy = p / 28, xx = p - yy * 28;
  size_t mp = 31 + (size_t)b * 841 + (size_t)yy * 29 + xx;
  union { int8_t b8[8]; ull u; } o;
#pragma unroll
  for (int j = 0; j < 8; ++j) {
    int c = cb + j;
    float z = ((float)v[j] - params[c * 2]) * params[c * 2 + 1] + beta[c];
    o.b8[j] = (int8_t)((z > 0.f) - (z < 0.f));
  }
  *(ull*)(xbp + mp * 256 + cb) = o.u;
}

// ---------------------------------------------------------------- BN2 + resid
// out NCHW f32 = (y2 - mean)*inv + beta + x ; y2 read compact NHWC, transposed
__global__ __launch_bounds__(256) void bn_residual(const int16_t* __restrict__ y,
                                                   const float* __restrict__ params,
                                                   const float* __restrict__ beta,
                                                   const float* __restrict__ x,
                                                   float* __restrict__ out) {
  const int mt = blockIdx.x, ct = blockIdx.y;
  __shared__ int16_t sh[64][66];
  const int t = threadIdx.x;
  const int tl = t & 63, th = t >> 6;
#pragma unroll
  for (int i = 0; i < 16; ++i) {
    int ml = th + i * 4;
    sh[ml][tl] = y[(size_t)(mt * 64 + ml) * 256 + ct * 64 + tl];  // coalesced
  }
  __syncthreads();
#pragma unroll
  for (int i = 0; i < 16; ++i) {
    int cl = th + i * 4;
    int c = ct * 64 + cl;
    int m = mt * 64 + tl;
    int b = m / HW, p = m - b * HW;
    size_t oi = ((size_t)b * 256 + c) * HW + p;
    float z = ((float)sh[tl][cl] - params[c * 2]) * params[c * 2 + 1] + beta[c];
    out[oi] = z + x[oi];                         // coalesced along p
  }
}

// ---------------------------------------------------------------- launch
extern "C" void kernel_launch(void* const* d_in, const int* in_sizes, int n_in,
                              void* d_out, int out_size, void* d_ws, size_t ws_size,
                              hipStream_t stream) {
  const float* x      = (const float*)d_in[0];
  const float* w1     = (const float*)d_in[1];
  const float* gamma1 = (const float*)d_in[3];
  const float* beta1  = (const float*)d_in[4];
  const float* w2     = (const float*)d_in[5];
  const float* gamma2 = (const float*)d_in[7];
  const float* beta2  = (const float*)d_in[8];
  float* out = (float*)d_out;

  // ws layout (bytes):
  char* ws = (char*)d_ws;
  int8_t*  zp      = (int8_t*)ws;                       //        0 : 4096
  int8_t*  wb1     = (int8_t*)(ws + 4096);              //   589824
  int8_t*  wb2     = (int8_t*)(ws + 593920);            //   589824
  float*   params1 = (float*)(ws + 1183744);            //     2048
  float*   params2 = (float*)(ws + 1185792);            //     2048
  ull*     stats1  = (ull*)(ws + 1187840);              //   131072
  ull*     stats2  = (ull*)(ws + 1318912);              //   131072
  int8_t*  xbp     = (int8_t*)(ws + 1449984);           // 13803776 (padded, shared)
  int16_t* yb      = (int16_t*)(ws + 15253760);         // 25690112 (y1/y2 reused)
  if (ws_size < 40943872ull) return;                    // ~39.0 MiB scratch

  dim3 tr(784, 4);
  prep<<<7810, 256, 0, stream>>>(w1, w2, wb1, wb2, (int4v*)zp, stats1, x, xbp);
  bconv_mfma<<<NBLK, 256, 0, stream>>>(xbp, wb1, yb, stats1, zp);
  bn_params<<<1, 256, 0, stream>>>(stats1, gamma1, params1);
  bin_mid<<<6272, 256, 0, stream>>>(yb, params1, beta1, xbp);
  bconv_mfma<<<NBLK, 256, 0, stream>>>(xbp, wb2, yb, stats2, zp);
  bn_params<<<1, 256, 0, stream>>>(stats2, gamma2, params2);
  bn_residual<<<tr, 256, 0, stream>>>(yb, params2, beta2, x, out);
}